// Round 1
// baseline (181.846 us; speedup 1.0000x reference)
//
#include <hip/hip_runtime.h>

#define BATCH 8192
#define NNB 100

// P-table row offsets (cumulative table rows * 67). Tables: lang(50), plat(5),
// os(30), country(200), carrier(500), brand(2000), plat_os(100) => 2885 rows.
#define T1 3350
#define T2 3685
#define T3 5695
#define T4 19095
#define T5 52595
#define T6 186595
#define PSZ 193295  // 2885*67

// Static device storage (graph-capture safe, no hipMalloc).
__device__ float g_Pmsg[PSZ];
__device__ float g_Pdev1[PSZ];
__device__ float g_w0b_msg[134];   // [0:67]=W_msg[:,0], [67:134]=b_msg
__device__ float g_w0b_dev1[134];
// Transposed weights, padded to output-stride 64 (zeros beyond O).
__device__ float g_Wt_ch1[46 * 64];
__device__ float g_Wt_dev2[67 * 64];
__device__ float g_Wt_fus[94 * 64];
__device__ float g_Wt_c1[106 * 64];
__device__ float g_Wt_c2[63 * 64];
__device__ float g_bpad[5 * 64];   // padded biases: ch1, dev2, fus, c1, c2

__device__ __forceinline__ float rl(float v, int k) {
    return __uint_as_float(__builtin_amdgcn_readlane(__float_as_uint(v), (unsigned)k));
}

// ---------------------------------------------------------------------------
// Kernel A: build projected embedding tables, transposed/padded weights, and
// packed (W[:,0], b) arrays. One thread per output element, grid-stride-free.
// Index space: [0, 2*PSZ) proj | [.., +24064) transpose | +320 bias | +268 pack
// ---------------------------------------------------------------------------
__global__ __launch_bounds__(256) void prep_kernel(
    const float* __restrict__ lang, const float* __restrict__ plat,
    const float* __restrict__ osb, const float* __restrict__ country,
    const float* __restrict__ carrier, const float* __restrict__ brand,
    const float* __restrict__ plat_os,
    const float* __restrict__ Wmsg, const float* __restrict__ bmsg,
    const float* __restrict__ Wdev1, const float* __restrict__ bdev1,
    const float* __restrict__ Wch1, const float* __restrict__ bch1,
    const float* __restrict__ Wdev2, const float* __restrict__ bdev2,
    const float* __restrict__ Wfus, const float* __restrict__ bfus,
    const float* __restrict__ Wc1, const float* __restrict__ bc1,
    const float* __restrict__ Wc2, const float* __restrict__ bc2)
{
    int idx = blockIdx.x * 256 + threadIdx.x;
    const int NPROJ = 2 * PSZ;
    if (idx < NPROJ) {
        int which = idx / PSZ;            // 0 = msg, 1 = dev1
        int rem = idx - which * PSZ;
        int row = rem / 67;
        int o = rem - row * 67;
        int t, r;
        if (row < 50)        { t = 0; r = row; }
        else if (row < 55)   { t = 1; r = row - 50; }
        else if (row < 85)   { t = 2; r = row - 55; }
        else if (row < 285)  { t = 3; r = row - 85; }
        else if (row < 785)  { t = 4; r = row - 285; }
        else if (row < 2785) { t = 5; r = row - 785; }
        else                 { t = 6; r = row - 2785; }
        const float* tab;
        switch (t) {
            case 0: tab = lang; break;    case 1: tab = plat; break;
            case 2: tab = osb; break;     case 3: tab = country; break;
            case 4: tab = carrier; break; case 5: tab = brand; break;
            default: tab = plat_os;
        }
        const float* e = tab + r * 16;
        const float* W = (which ? Wdev1 : Wmsg) + o * 113 + 1 + 16 * t;
        float s = 0.f;
#pragma unroll
        for (int j = 0; j < 16; j++) s += e[j] * W[j];
        (which ? g_Pdev1 : g_Pmsg)[rem] = s;
        return;
    }
    int l = idx - NPROJ;
    if (l < 2944) { int k = l >> 6, o = l & 63; g_Wt_ch1[l]  = (o < 27) ? Wch1[o * 46 + k]  : 0.f; return; }
    l -= 2944;
    if (l < 4288) { int k = l >> 6, o = l & 63; g_Wt_dev2[l] = (o < 50) ? Wdev2[o * 67 + k] : 0.f; return; }
    l -= 4288;
    if (l < 6016) { int k = l >> 6, o = l & 63; g_Wt_fus[l]  = (o < 56) ? Wfus[o * 94 + k]  : 0.f; return; }
    l -= 6016;
    if (l < 6784) { int k = l >> 6, o = l & 63; g_Wt_c1[l]   = (o < 63) ? Wc1[o * 106 + k]  : 0.f; return; }
    l -= 6784;
    if (l < 4032) { int k = l >> 6, o = l & 63; g_Wt_c2[l]   = (o < 31) ? Wc2[o * 63 + k]   : 0.f; return; }
    l -= 4032;
    if (l < 320) {
        int which = l >> 6, o = l & 63;
        const float* b; int O;
        switch (which) {
            case 0: b = bch1; O = 27; break;  case 1: b = bdev2; O = 50; break;
            case 2: b = bfus; O = 56; break;  case 3: b = bc1; O = 63; break;
            default: b = bc2; O = 31;
        }
        g_bpad[l] = (o < O) ? b[o] : 0.f;
        return;
    }
    l -= 320;
    if (l < 268) {
        int which = l / 134, k = l - which * 134;
        float* dst = which ? g_w0b_dev1 : g_w0b_msg;
        const float* W = which ? Wdev1 : Wmsg;
        const float* b = which ? bdev1 : bmsg;
        dst[k] = (k < 67) ? W[k * 113] : b[k - 67];
    }
}

// ---------------------------------------------------------------------------
// Kernel B: one wave per edge. Phase 1: neighbor message mean via projected
// table lookups (coalesced, L2-resident). Phase 2: whole per-edge MLP in
// registers; lane = output neuron; input broadcast via v_readlane; weights
// transposed/padded so every weight load is a coalesced 256B L1/L2 hit.
// ---------------------------------------------------------------------------
__global__ __launch_bounds__(256) void fused_kernel(
    const float* __restrict__ combin_feats, const float* __restrict__ dev_feats,
    const float* __restrict__ chemb,
    const int* __restrict__ edges, const int* __restrict__ neibrs,
    const float* __restrict__ Wc3, const float* __restrict__ bc3,
    float* __restrict__ out)
{
    int gid = blockIdx.x * 256 + threadIdx.x;
    int e = gid >> 6;
    int lane = threadIdx.x & 63;
    if (e >= BATCH) return;
    bool has2 = lane < 3;   // lanes 0..2 also own outputs 64..66

    // ---- Phase 1: msg = mean_j relu(b + cont*w0 + sum_t Pmsg[c_t]) ----
    float mw0  = g_w0b_msg[lane];
    float mb   = g_w0b_msg[67 + lane];
    float mw0b = has2 ? g_w0b_msg[64 + lane] : 0.f;
    float mbb  = has2 ? g_w0b_msg[131 + lane] : 0.f;
    const int* nb = neibrs + e * NNB;
    float acc0 = 0.f, acc1 = 0.f;
    for (int j = 0; j < NNB; j++) {
        int n = nb[j];
        const float4* dr = (const float4*)(dev_feats + (size_t)n * 8);
        float4 a = dr[0], b4 = dr[1];
        int c0 = (int)a.y * 67, c1 = (int)a.z * 67, c2 = (int)a.w * 67;
        int c3 = (int)b4.x * 67, c4 = (int)b4.y * 67, c5 = (int)b4.z * 67, c6 = (int)b4.w * 67;
        float v = mb + a.x * mw0
                + g_Pmsg[c0 + lane]      + g_Pmsg[T1 + c1 + lane]
                + g_Pmsg[T2 + c2 + lane] + g_Pmsg[T3 + c3 + lane]
                + g_Pmsg[T4 + c4 + lane] + g_Pmsg[T5 + c5 + lane]
                + g_Pmsg[T6 + c6 + lane];
        acc0 += fmaxf(v, 0.f);
        if (has2) {
            int l2 = 64 + lane;
            float v2 = mbb + a.x * mw0b
                     + g_Pmsg[c0 + l2]      + g_Pmsg[T1 + c1 + l2]
                     + g_Pmsg[T2 + c2 + l2] + g_Pmsg[T3 + c3 + l2]
                     + g_Pmsg[T4 + c4 + l2] + g_Pmsg[T5 + c5 + l2]
                     + g_Pmsg[T6 + c6 + l2];
            acc1 += fmaxf(v2, 0.f);
        }
    }
    float msg_a = acc0 * 0.01f;
    float msg_b = acc1 * 0.01f;   // lanes 0..2: outputs 64..66

    // ---- Phase 2: per-edge MLP, all activations in registers ----
    int e0 = edges[2 * e], e1 = edges[2 * e + 1];

    // combin_x (46 features) padded to 64 lanes
    const float* crow = combin_feats + (size_t)e0 * 31;
    int chid = (int)crow[30];
    float cx = 0.f;
    if (lane < 30)      cx = crow[lane];
    else if (lane < 46) cx = chemb[(size_t)chid * 16 + (lane - 30)];

    // d1 = relu(W_dev1 @ dev_x + b) via projected tables
    const float4* dr = (const float4*)(dev_feats + (size_t)e1 * 8);
    float4 a = dr[0], b4 = dr[1];
    int c0 = (int)a.y * 67, c1 = (int)a.z * 67, c2 = (int)a.w * 67;
    int c3 = (int)b4.x * 67, c4 = (int)b4.y * 67, c5 = (int)b4.z * 67, c6 = (int)b4.w * 67;
    float d1a, d1b = 0.f;
    {
        float v = g_w0b_dev1[67 + lane] + a.x * g_w0b_dev1[lane]
                + g_Pdev1[c0 + lane]      + g_Pdev1[T1 + c1 + lane]
                + g_Pdev1[T2 + c2 + lane] + g_Pdev1[T3 + c3 + lane]
                + g_Pdev1[T4 + c4 + lane] + g_Pdev1[T5 + c5 + lane]
                + g_Pdev1[T6 + c6 + lane];
        d1a = fmaxf(v, 0.f);
        if (has2) {
            int l2 = 64 + lane;
            float v2 = g_w0b_dev1[131 + lane] + a.x * g_w0b_dev1[64 + lane]
                     + g_Pdev1[c0 + l2]      + g_Pdev1[T1 + c1 + l2]
                     + g_Pdev1[T2 + c2 + l2] + g_Pdev1[T3 + c3 + l2]
                     + g_Pdev1[T4 + c4 + l2] + g_Pdev1[T5 + c5 + l2]
                     + g_Pdev1[T6 + c6 + l2];
            d1b = fmaxf(v2, 0.f);
        }
    }

    // ch = relu(W_ch1 @ combin_x + b)   I=46, O=27
    float s = g_bpad[lane];
    for (int k = 0; k < 46; k++) s += rl(cx, k) * g_Wt_ch1[k * 64 + lane];
    float ch = fmaxf(s, 0.f);

    // d2 = relu(W_dev2 @ d1 + b)        I=67, O=50
    s = g_bpad[64 + lane];
    for (int k = 0; k < 64; k++) s += rl(d1a, k) * g_Wt_dev2[k * 64 + lane];
    for (int k = 0; k < 3; k++)  s += rl(d1b, k) * g_Wt_dev2[(64 + k) * 64 + lane];
    float d2 = fmaxf(s, 0.f);

    // fus = relu(W_fus @ [ch|msg] + b)  I=94, O=56
    s = g_bpad[128 + lane];
    for (int k = 0; k < 27; k++) s += rl(ch, k) * g_Wt_fus[k * 64 + lane];
    for (int k = 0; k < 64; k++) s += rl(msg_a, k) * g_Wt_fus[(27 + k) * 64 + lane];
    for (int k = 0; k < 3; k++)  s += rl(msg_b, k) * g_Wt_fus[(91 + k) * 64 + lane];
    float fus = fmaxf(s, 0.f);

    // h1 = relu(W_c1 @ [fus|d2] + b)    I=106, O=63
    s = g_bpad[192 + lane];
    for (int k = 0; k < 56; k++) s += rl(fus, k) * g_Wt_c1[k * 64 + lane];
    for (int k = 0; k < 50; k++) s += rl(d2, k) * g_Wt_c1[(56 + k) * 64 + lane];
    float h1 = fmaxf(s, 0.f);

    // h2 = relu(W_c2 @ h1 + b)          I=63, O=31
    s = g_bpad[256 + lane];
    for (int k = 0; k < 63; k++) s += rl(h1, k) * g_Wt_c2[k * 64 + lane];
    float h2 = fmaxf(s, 0.f);

    // out = W_c3 @ h2 + b  (wave butterfly reduction)
    float t = (lane < 31) ? h2 * Wc3[lane] : 0.f;
    for (int off = 32; off; off >>= 1) t += __shfl_xor(t, off);
    if (lane == 0) out[e] = t + bc3[0];
}

extern "C" void kernel_launch(void* const* d_in, const int* in_sizes, int n_in,
                              void* d_out, int out_size, void* d_ws, size_t ws_size,
                              hipStream_t stream) {
    const float* combin   = (const float*)d_in[0];
    const float* devf     = (const float*)d_in[1];
    const float* chemb    = (const float*)d_in[2];
    const float* lang     = (const float*)d_in[3];
    const float* plat     = (const float*)d_in[4];
    const float* osb      = (const float*)d_in[5];
    const float* country  = (const float*)d_in[6];
    const float* carrier  = (const float*)d_in[7];
    const float* brand    = (const float*)d_in[8];
    const float* plat_os  = (const float*)d_in[9];
    const float* Wch1 = (const float*)d_in[10]; const float* bch1 = (const float*)d_in[11];
    const float* Wmsg = (const float*)d_in[12]; const float* bmsg = (const float*)d_in[13];
    const float* Wfus = (const float*)d_in[14]; const float* bfus = (const float*)d_in[15];
    const float* Wdev1 = (const float*)d_in[16]; const float* bdev1 = (const float*)d_in[17];
    const float* Wdev2 = (const float*)d_in[18]; const float* bdev2 = (const float*)d_in[19];
    const float* Wc1 = (const float*)d_in[20]; const float* bc1 = (const float*)d_in[21];
    const float* Wc2 = (const float*)d_in[22]; const float* bc2 = (const float*)d_in[23];
    const float* Wc3 = (const float*)d_in[24]; const float* bc3 = (const float*)d_in[25];
    const int* edges  = (const int*)d_in[26];
    const int* neibrs = (const int*)d_in[27];
    float* out = (float*)d_out;

    // prep: 2*193295 proj + 24064 transpose + 320 bias-pad + 268 pack = 411242
    int prep_threads = 2 * PSZ + 24064 + 320 + 268;
    int prep_blocks = (prep_threads + 255) / 256;
    prep_kernel<<<prep_blocks, 256, 0, stream>>>(
        lang, plat, osb, country, carrier, brand, plat_os,
        Wmsg, bmsg, Wdev1, bdev1, Wch1, bch1, Wdev2, bdev2,
        Wfus, bfus, Wc1, bc1, Wc2, bc2);

    fused_kernel<<<BATCH / 4, 256, 0, stream>>>(
        combin, devf, chemb, edges, neibrs, Wc3, bc3, out);
}

// Round 2
// 179.313 us; speedup vs baseline: 1.0141x; 1.0141x over previous
//
#include <hip/hip_runtime.h>

#define BATCH 8192
#define NNB 100
#define NDEV 1000000

// P-table row offsets (cumulative rows * 67): lang(50), plat(5), os(30),
// country(200), carrier(500), brand(2000), plat_os(100) => 2885 rows.
#define T1 3350
#define T2 3685
#define T3 5695
#define T4 19095
#define T5 52595
#define T6 186595
#define PSZ 193295  // 2885*67

// Static device storage (graph-capture safe). +64 pad allows unconditional
// tail (+256B) loads; pad is .bss-zero and never written => always finite.
__device__ float g_Pmsg[PSZ + 64];
__device__ float g_Pdev1[PSZ + 64];
__device__ float g_w0b_msg[256];    // [0:67]=W[:,0], [67:134]=b, rest 0
__device__ float g_w0b_dev1[256];
__device__ uint4 g_pack[NDEV];      // {cont_f32, lo_idx, hi_idx, 0}
// Transposed weights, padded to output-stride 64 (zeros beyond O).
__device__ float g_Wt_ch1[46 * 64];
__device__ float g_Wt_dev2[67 * 64];
__device__ float g_Wt_fus[94 * 64];
__device__ float g_Wt_c1[106 * 64];
__device__ float g_Wt_c2[63 * 64];
__device__ float g_bpad[5 * 64];

__device__ __forceinline__ float rl(float v, int k) {
    return __uint_as_float(__builtin_amdgcn_readlane(__float_as_uint(v), (unsigned)k));
}

// Per-device projected lookup: 7 packed indices -> sum of 7 P-rows + cont*w0 + b,
// relu. Outputs o1 = dims [lane], o2 = dims [64+lane] (valid for lane<3 only;
// other lanes produce finite garbage that is never consumed).
__device__ __forceinline__ void accum_pair(const float* __restrict__ P, uint4 r,
    float w0a, float ba, float w0b, float bb, int lane, float& o1, float& o2)
{
    float cont = __uint_as_float(r.x);
    unsigned lo = r.y, hi = r.z;
    int i0 = (int)(lo & 255u) * 67;                 // lang
    int i1 = T1 + (int)((lo >> 8) & 255u) * 67;     // plat
    int i2 = T2 + (int)((lo >> 16) & 255u) * 67;    // os
    int i6 = T6 + (int)(lo >> 24) * 67;             // plat_os
    int i3 = T3 + (int)(hi & 511u) * 67;            // country
    int i4 = T4 + (int)((hi >> 9) & 511u) * 67;     // carrier
    int i5 = T5 + (int)(hi >> 20) * 67;             // brand
    const float* p = P + lane;
    float v = ba + cont * w0a
            + p[i0] + p[i1] + p[i2] + p[i3] + p[i4] + p[i5] + p[i6];
    o1 = fmaxf(v, 0.f);
    const float* q = p + 64;   // same addresses + offset:256
    float v2 = bb + cont * w0b
             + q[i0] + q[i1] + q[i2] + q[i3] + q[i4] + q[i5] + q[i6];
    o2 = fmaxf(v2, 0.f);
}

// ---------------------------------------------------------------------------
// Kernel A: pack device rows, build projected embedding tables, transposed/
// padded weights, packed (W[:,0], b). One thread per output element.
// Index space: [0,NDEV) pack | [..,+2*PSZ) proj | +24064 transpose | +320 | +268
// ---------------------------------------------------------------------------
__global__ __launch_bounds__(256) void prep_kernel(
    const float* __restrict__ devf,
    const float* __restrict__ lang, const float* __restrict__ plat,
    const float* __restrict__ osb, const float* __restrict__ country,
    const float* __restrict__ carrier, const float* __restrict__ brand,
    const float* __restrict__ plat_os,
    const float* __restrict__ Wmsg, const float* __restrict__ bmsg,
    const float* __restrict__ Wdev1, const float* __restrict__ bdev1,
    const float* __restrict__ Wch1, const float* __restrict__ bch1,
    const float* __restrict__ Wdev2, const float* __restrict__ bdev2,
    const float* __restrict__ Wfus, const float* __restrict__ bfus,
    const float* __restrict__ Wc1, const float* __restrict__ bc1,
    const float* __restrict__ Wc2, const float* __restrict__ bc2)
{
    int idx = blockIdx.x * 256 + threadIdx.x;
    if (idx < NDEV) {
        const float4* dr = (const float4*)(devf + (size_t)idx * 8);
        float4 a = dr[0], b4 = dr[1];
        unsigned lo = (unsigned)a.y | ((unsigned)a.z << 8)
                    | ((unsigned)a.w << 16) | ((unsigned)b4.w << 24);
        unsigned hi = (unsigned)b4.x | ((unsigned)b4.y << 9)
                    | ((unsigned)b4.z << 20);
        g_pack[idx] = make_uint4(__float_as_uint(a.x), lo, hi, 0u);
        return;
    }
    idx -= NDEV;
    const int NPROJ = 2 * PSZ;
    if (idx < NPROJ) {
        int which = idx / PSZ;            // 0 = msg, 1 = dev1
        int rem = idx - which * PSZ;
        int row = rem / 67;
        int o = rem - row * 67;
        int t, r;
        if (row < 50)        { t = 0; r = row; }
        else if (row < 55)   { t = 1; r = row - 50; }
        else if (row < 85)   { t = 2; r = row - 55; }
        else if (row < 285)  { t = 3; r = row - 85; }
        else if (row < 785)  { t = 4; r = row - 285; }
        else if (row < 2785) { t = 5; r = row - 785; }
        else                 { t = 6; r = row - 2785; }
        const float* tab;
        switch (t) {
            case 0: tab = lang; break;    case 1: tab = plat; break;
            case 2: tab = osb; break;     case 3: tab = country; break;
            case 4: tab = carrier; break; case 5: tab = brand; break;
            default: tab = plat_os;
        }
        const float* e = tab + r * 16;
        const float* W = (which ? Wdev1 : Wmsg) + o * 113 + 1 + 16 * t;
        float s = 0.f;
#pragma unroll
        for (int j = 0; j < 16; j++) s += e[j] * W[j];
        (which ? g_Pdev1 : g_Pmsg)[rem] = s;
        return;
    }
    int l = idx - NPROJ;
    if (l < 2944) { int k = l >> 6, o = l & 63; g_Wt_ch1[l]  = (o < 27) ? Wch1[o * 46 + k]  : 0.f; return; }
    l -= 2944;
    if (l < 4288) { int k = l >> 6, o = l & 63; g_Wt_dev2[l] = (o < 50) ? Wdev2[o * 67 + k] : 0.f; return; }
    l -= 4288;
    if (l < 6016) { int k = l >> 6, o = l & 63; g_Wt_fus[l]  = (o < 56) ? Wfus[o * 94 + k]  : 0.f; return; }
    l -= 6016;
    if (l < 6784) { int k = l >> 6, o = l & 63; g_Wt_c1[l]   = (o < 63) ? Wc1[o * 106 + k]  : 0.f; return; }
    l -= 6784;
    if (l < 4032) { int k = l >> 6, o = l & 63; g_Wt_c2[l]   = (o < 31) ? Wc2[o * 63 + k]   : 0.f; return; }
    l -= 4032;
    if (l < 320) {
        int which = l >> 6, o = l & 63;
        const float* b; int O;
        switch (which) {
            case 0: b = bch1; O = 27; break;  case 1: b = bdev2; O = 50; break;
            case 2: b = bfus; O = 56; break;  case 3: b = bc1; O = 63; break;
            default: b = bc2; O = 31;
        }
        g_bpad[l] = (o < O) ? b[o] : 0.f;
        return;
    }
    l -= 320;
    if (l < 268) {
        int which = l / 134, k = l - which * 134;
        float* dst = which ? g_w0b_dev1 : g_w0b_msg;
        const float* W = which ? Wdev1 : Wmsg;
        const float* b = which ? bdev1 : bmsg;
        dst[k] = (k < 67) ? W[k * 113] : b[k - 67];
    }
}

// ---------------------------------------------------------------------------
// Kernel B: one wave per edge. Phase 1: neighbor message mean via packed
// index rows + projected-table lookups (coalesced, L2-resident). Phase 2:
// whole per-edge MLP in registers; lane = output neuron.
// ---------------------------------------------------------------------------
__global__ __launch_bounds__(256) void fused_kernel(
    const float* __restrict__ combin_feats, const float* __restrict__ chemb,
    const int* __restrict__ edges, const int* __restrict__ neibrs,
    const float* __restrict__ Wc3, const float* __restrict__ bc3,
    float* __restrict__ out)
{
    int gid = blockIdx.x * 256 + threadIdx.x;
    int e = gid >> 6;
    int lane = threadIdx.x & 63;
    if (e >= BATCH) return;

    // ---- Phase 1: msg = mean_j relu(b + cont*w0 + sum_t Pmsg[c_t]) ----
    float mw0  = g_w0b_msg[lane];
    float mb   = g_w0b_msg[67 + lane];
    float mw0b = g_w0b_msg[64 + lane];    // valid for lane<3; finite otherwise
    float mbb  = g_w0b_msg[131 + lane];
    const int4* nb4 = (const int4*)(neibrs + (size_t)e * NNB);
    float acc0 = 0.f, acc1 = 0.f;
#pragma unroll 1
    for (int j4 = 0; j4 < NNB / 4; j4++) {
        int4 nn = nb4[j4];
        uint4 r0 = g_pack[nn.x], r1 = g_pack[nn.y];
        uint4 r2 = g_pack[nn.z], r3 = g_pack[nn.w];
        float u, v;
        accum_pair(g_Pmsg, r0, mw0, mb, mw0b, mbb, lane, u, v); acc0 += u; acc1 += v;
        accum_pair(g_Pmsg, r1, mw0, mb, mw0b, mbb, lane, u, v); acc0 += u; acc1 += v;
        accum_pair(g_Pmsg, r2, mw0, mb, mw0b, mbb, lane, u, v); acc0 += u; acc1 += v;
        accum_pair(g_Pmsg, r3, mw0, mb, mw0b, mbb, lane, u, v); acc0 += u; acc1 += v;
    }
    float msg_a = acc0 * 0.01f;
    float msg_b = acc1 * 0.01f;   // lanes 0..2: outputs 64..66

    // ---- Phase 2: per-edge MLP, all activations in registers ----
    int e0 = edges[2 * e], e1 = edges[2 * e + 1];

    // combin_x (46 features) padded to 64 lanes
    const float* crow = combin_feats + (size_t)e0 * 31;
    int chid = (int)crow[30];
    float cx = 0.f;
    if (lane < 30)      cx = crow[lane];
    else if (lane < 46) cx = chemb[(size_t)chid * 16 + (lane - 30)];

    // d1 = relu(W_dev1 @ dev_x + b) via packed row + projected tables
    float d1a, d1b;
    {
        uint4 r = g_pack[e1];
        accum_pair(g_Pdev1, r, g_w0b_dev1[lane], g_w0b_dev1[67 + lane],
                   g_w0b_dev1[64 + lane], g_w0b_dev1[131 + lane], lane, d1a, d1b);
    }

    // ch = relu(W_ch1 @ combin_x + b)   I=46, O=27
    float s = g_bpad[lane];
    for (int k = 0; k < 46; k++) s += rl(cx, k) * g_Wt_ch1[k * 64 + lane];
    float ch = fmaxf(s, 0.f);

    // d2 = relu(W_dev2 @ d1 + b)        I=67, O=50
    s = g_bpad[64 + lane];
    for (int k = 0; k < 64; k++) s += rl(d1a, k) * g_Wt_dev2[k * 64 + lane];
    for (int k = 0; k < 3; k++)  s += rl(d1b, k) * g_Wt_dev2[(64 + k) * 64 + lane];
    float d2 = fmaxf(s, 0.f);

    // fus = relu(W_fus @ [ch|msg] + b)  I=94, O=56
    s = g_bpad[128 + lane];
    for (int k = 0; k < 27; k++) s += rl(ch, k) * g_Wt_fus[k * 64 + lane];
    for (int k = 0; k < 64; k++) s += rl(msg_a, k) * g_Wt_fus[(27 + k) * 64 + lane];
    for (int k = 0; k < 3; k++)  s += rl(msg_b, k) * g_Wt_fus[(91 + k) * 64 + lane];
    float fus = fmaxf(s, 0.f);

    // h1 = relu(W_c1 @ [fus|d2] + b)    I=106, O=63
    s = g_bpad[192 + lane];
    for (int k = 0; k < 56; k++) s += rl(fus, k) * g_Wt_c1[k * 64 + lane];
    for (int k = 0; k < 50; k++) s += rl(d2, k) * g_Wt_c1[(56 + k) * 64 + lane];
    float h1 = fmaxf(s, 0.f);

    // h2 = relu(W_c2 @ h1 + b)          I=63, O=31
    s = g_bpad[256 + lane];
    for (int k = 0; k < 63; k++) s += rl(h1, k) * g_Wt_c2[k * 64 + lane];
    float h2 = fmaxf(s, 0.f);

    // out = W_c3 @ h2 + b  (wave butterfly reduction)
    float t = (lane < 31) ? h2 * Wc3[lane] : 0.f;
    for (int off = 32; off; off >>= 1) t += __shfl_xor(t, off);
    if (lane == 0) out[e] = t + bc3[0];
}

extern "C" void kernel_launch(void* const* d_in, const int* in_sizes, int n_in,
                              void* d_out, int out_size, void* d_ws, size_t ws_size,
                              hipStream_t stream) {
    const float* combin   = (const float*)d_in[0];
    const float* devf     = (const float*)d_in[1];
    const float* chemb    = (const float*)d_in[2];
    const float* lang     = (const float*)d_in[3];
    const float* plat     = (const float*)d_in[4];
    const float* osb      = (const float*)d_in[5];
    const float* country  = (const float*)d_in[6];
    const float* carrier  = (const float*)d_in[7];
    const float* brand    = (const float*)d_in[8];
    const float* plat_os  = (const float*)d_in[9];
    const float* Wch1 = (const float*)d_in[10]; const float* bch1 = (const float*)d_in[11];
    const float* Wmsg = (const float*)d_in[12]; const float* bmsg = (const float*)d_in[13];
    const float* Wfus = (const float*)d_in[14]; const float* bfus = (const float*)d_in[15];
    const float* Wdev1 = (const float*)d_in[16]; const float* bdev1 = (const float*)d_in[17];
    const float* Wdev2 = (const float*)d_in[18]; const float* bdev2 = (const float*)d_in[19];
    const float* Wc1 = (const float*)d_in[20]; const float* bc1 = (const float*)d_in[21];
    const float* Wc2 = (const float*)d_in[22]; const float* bc2 = (const float*)d_in[23];
    const float* Wc3 = (const float*)d_in[24]; const float* bc3 = (const float*)d_in[25];
    const int* edges  = (const int*)d_in[26];
    const int* neibrs = (const int*)d_in[27];
    float* out = (float*)d_out;

    // prep: NDEV pack + 2*PSZ proj + 24064 transpose + 320 bias + 268 pack
    long long prep_threads = (long long)NDEV + 2LL * PSZ + 24064 + 320 + 268;
    int prep_blocks = (int)((prep_threads + 255) / 256);
    prep_kernel<<<prep_blocks, 256, 0, stream>>>(
        devf, lang, plat, osb, country, carrier, brand, plat_os,
        Wmsg, bmsg, Wdev1, bdev1, Wch1, bch1, Wdev2, bdev2,
        Wfus, bfus, Wc1, bc1, Wc2, bc2);

    fused_kernel<<<BATCH / 4, 256, 0, stream>>>(
        combin, chemb, edges, neibrs, Wc3, bc3, out);
}

// Round 3
// 111.037 us; speedup vs baseline: 1.6377x; 1.6149x over previous
//
#include <hip/hip_runtime.h>
#include <hip/hip_fp16.h>

#define BATCH 8192
#define NNB 100
#define NDEV 1000000

// Projected-table geometry: 2885 rows (lang 50, plat 5, os 30, country 200,
// carrier 500, brand 2000, plat_os 100), 67 output dims per row.
// Interleaved layout: g_P2*[row*64 + l] = f16(P[row][l]) | f16(P[row][64+l])<<16
// (high half is exact 0 for l>=3).
#define NROWS 2885
#define NP2HALF (NROWS * 64)   // 184640

// Static device storage (graph-capture safe).
__device__ unsigned g_P2msg[NP2HALF];
__device__ unsigned g_P2dev1[NP2HALF];
__device__ float g_w0b_msg[256];    // [0:67]=W[:,0], [67:134]=b, rest 0
__device__ float g_w0b_dev1[256];
__device__ uint4 g_pack[NDEV];      // {cont_f32, lo_idx, hi_idx, 0}
// Transposed weights, padded to output-stride 64 (zeros beyond O).
__device__ float g_Wt_ch1[46 * 64];
__device__ float g_Wt_dev2[67 * 64];
__device__ float g_Wt_fus[94 * 64];
__device__ float g_Wt_c1[106 * 64];
__device__ float g_Wt_c2[63 * 64];
__device__ float g_bpad[5 * 64];

__device__ __forceinline__ float rl(float v, int k) {
    return __uint_as_float(__builtin_amdgcn_readlane(__float_as_uint(v), (unsigned)k));
}

// One device's projected lookup: 7 interleaved-f16 gathers; lane l accumulates
// relu into acc0 (dim l) and acc1 (dim 64+l; exact for lane<3, zero-padded sum
// plus garbage bias for lanes>=3 -- never consumed).
__device__ __forceinline__ void accum_one(const unsigned* __restrict__ P2, uint4 r,
    float mw0, float mb, float mw0b, float mbb, int lane, float& acc0, float& acc1)
{
    float cont = __uint_as_float(r.x);
    unsigned lo = r.y, hi = r.z;
    int b0 = ((int)(lo & 255u)) << 6;                  // lang   (rows 0..)
    int b1 = (50   + (int)((lo >> 8) & 255u)) << 6;    // plat
    int b2 = (55   + (int)((lo >> 16) & 255u)) << 6;   // os
    int b6 = (2785 + (int)(lo >> 24)) << 6;            // plat_os
    int b3 = (85   + (int)(hi & 511u)) << 6;           // country
    int b4 = (285  + (int)((hi >> 9) & 511u)) << 6;    // carrier
    int b5 = (785  + (int)(hi >> 20)) << 6;            // brand
    unsigned u0 = P2[b0 + lane], u1 = P2[b1 + lane], u2 = P2[b2 + lane];
    unsigned u3 = P2[b3 + lane], u4 = P2[b4 + lane], u5 = P2[b5 + lane];
    unsigned u6 = P2[b6 + lane];
    float vm = fmaf(cont, mw0, mb);
    float vt = fmaf(cont, mw0b, mbb);
    float2 f;
    f = __half22float2(*reinterpret_cast<const __half2*>(&u0)); vm += f.x; vt += f.y;
    f = __half22float2(*reinterpret_cast<const __half2*>(&u1)); vm += f.x; vt += f.y;
    f = __half22float2(*reinterpret_cast<const __half2*>(&u2)); vm += f.x; vt += f.y;
    f = __half22float2(*reinterpret_cast<const __half2*>(&u3)); vm += f.x; vt += f.y;
    f = __half22float2(*reinterpret_cast<const __half2*>(&u4)); vm += f.x; vt += f.y;
    f = __half22float2(*reinterpret_cast<const __half2*>(&u5)); vm += f.x; vt += f.y;
    f = __half22float2(*reinterpret_cast<const __half2*>(&u6)); vm += f.x; vt += f.y;
    acc0 += fmaxf(vm, 0.f);
    acc1 += fmaxf(vt, 0.f);
}

// ---------------------------------------------------------------------------
// Kernel A: pack device rows, build interleaved projected tables, transposed/
// padded weights, packed (W[:,0], b). One thread per output element.
// ---------------------------------------------------------------------------
__global__ __launch_bounds__(256) void prep_kernel(
    const float* __restrict__ devf,
    const float* __restrict__ lang, const float* __restrict__ plat,
    const float* __restrict__ osb, const float* __restrict__ country,
    const float* __restrict__ carrier, const float* __restrict__ brand,
    const float* __restrict__ plat_os,
    const float* __restrict__ Wmsg, const float* __restrict__ bmsg,
    const float* __restrict__ Wdev1, const float* __restrict__ bdev1,
    const float* __restrict__ Wch1, const float* __restrict__ bch1,
    const float* __restrict__ Wdev2, const float* __restrict__ bdev2,
    const float* __restrict__ Wfus, const float* __restrict__ bfus,
    const float* __restrict__ Wc1, const float* __restrict__ bc1,
    const float* __restrict__ Wc2, const float* __restrict__ bc2)
{
    int idx = blockIdx.x * 256 + threadIdx.x;
    if (idx < NDEV) {
        const float4* dr = (const float4*)(devf + (size_t)idx * 8);
        float4 a = dr[0], b4 = dr[1];
        unsigned lo = (unsigned)a.y | ((unsigned)a.z << 8)
                    | ((unsigned)a.w << 16) | ((unsigned)b4.w << 24);
        unsigned hi = (unsigned)b4.x | ((unsigned)b4.y << 9)
                    | ((unsigned)b4.z << 20);
        g_pack[idx] = make_uint4(__float_as_uint(a.x), lo, hi, 0u);
        return;
    }
    idx -= NDEV;
    if (idx < 2 * NP2HALF) {
        int which = idx / NP2HALF;        // 0 = msg, 1 = dev1
        int rem = idx - which * NP2HALF;
        int row = rem >> 6;
        int l = rem & 63;
        int t, r;
        if (row < 50)        { t = 0; r = row; }
        else if (row < 55)   { t = 1; r = row - 50; }
        else if (row < 85)   { t = 2; r = row - 55; }
        else if (row < 285)  { t = 3; r = row - 85; }
        else if (row < 785)  { t = 4; r = row - 285; }
        else if (row < 2785) { t = 5; r = row - 785; }
        else                 { t = 6; r = row - 2785; }
        const float* tab;
        switch (t) {
            case 0: tab = lang; break;    case 1: tab = plat; break;
            case 2: tab = osb; break;     case 3: tab = country; break;
            case 4: tab = carrier; break; case 5: tab = brand; break;
            default: tab = plat_os;
        }
        const float* e = tab + r * 16;
        const float* W = (which ? Wdev1 : Wmsg);
        const float* Wm = W + l * 113 + 1 + 16 * t;
        float m = 0.f;
#pragma unroll
        for (int j = 0; j < 16; j++) m += e[j] * Wm[j];
        float tl = 0.f;
        if (l < 3) {
            const float* Wt2 = W + (64 + l) * 113 + 1 + 16 * t;
#pragma unroll
            for (int j = 0; j < 16; j++) tl += e[j] * Wt2[j];
        }
        unsigned pm = (unsigned)__half_as_ushort(__float2half(m));
        unsigned pt = (unsigned)__half_as_ushort(__float2half(tl));
        (which ? g_P2dev1 : g_P2msg)[rem] = pm | (pt << 16);
        return;
    }
    int l = idx - 2 * NP2HALF;
    if (l < 2944) { int k = l >> 6, o = l & 63; g_Wt_ch1[l]  = (o < 27) ? Wch1[o * 46 + k]  : 0.f; return; }
    l -= 2944;
    if (l < 4288) { int k = l >> 6, o = l & 63; g_Wt_dev2[l] = (o < 50) ? Wdev2[o * 67 + k] : 0.f; return; }
    l -= 4288;
    if (l < 6016) { int k = l >> 6, o = l & 63; g_Wt_fus[l]  = (o < 56) ? Wfus[o * 94 + k]  : 0.f; return; }
    l -= 6016;
    if (l < 6784) { int k = l >> 6, o = l & 63; g_Wt_c1[l]   = (o < 63) ? Wc1[o * 106 + k]  : 0.f; return; }
    l -= 6784;
    if (l < 4032) { int k = l >> 6, o = l & 63; g_Wt_c2[l]   = (o < 31) ? Wc2[o * 63 + k]   : 0.f; return; }
    l -= 4032;
    if (l < 320) {
        int which = l >> 6, o = l & 63;
        const float* b; int O;
        switch (which) {
            case 0: b = bch1; O = 27; break;  case 1: b = bdev2; O = 50; break;
            case 2: b = bfus; O = 56; break;  case 3: b = bc1; O = 63; break;
            default: b = bc2; O = 31;
        }
        g_bpad[l] = (o < O) ? b[o] : 0.f;
        return;
    }
    l -= 320;
    if (l < 268) {
        int which = l / 134, k = l - which * 134;
        float* dst = which ? g_w0b_dev1 : g_w0b_msg;
        const float* W = which ? Wdev1 : Wmsg;
        const float* b = which ? bdev1 : bmsg;
        dst[k] = (k < 67) ? W[k * 113] : b[k - 67];
    }
}

// ---------------------------------------------------------------------------
// Kernel B: one wave per edge. Phase 1: neighbor mean via readlane-broadcast
// indices (uniform pack loads, software-pipelined one group of 4 ahead) +
// interleaved-f16 projected-table gathers. Phase 2: per-edge MLP in registers.
// ---------------------------------------------------------------------------
__global__ __launch_bounds__(256) void fused_kernel(
    const float* __restrict__ combin_feats, const float* __restrict__ chemb,
    const int* __restrict__ edges, const int* __restrict__ neibrs,
    const float* __restrict__ Wc3, const float* __restrict__ bc3,
    float* __restrict__ out)
{
    int gid = blockIdx.x * 256 + threadIdx.x;
    int e = gid >> 6;
    int lane = threadIdx.x & 63;

    // Preload the whole neighbor list into 2 VGPRs (per-lane slots).
    const int* nb = neibrs + (size_t)e * NNB;
    int j_a = nb[lane];
    int jb_i = 64 + lane; if (jb_i > NNB - 1) jb_i = NNB - 1;
    int j_b = nb[jb_i];

    float mw0  = g_w0b_msg[lane];
    float mb   = g_w0b_msg[67 + lane];
    float mw0b = g_w0b_msg[64 + lane];    // valid lane<3; finite otherwise
    float mbb  = g_w0b_msg[131 + lane];

    float acc0 = 0.f, acc1 = 0.f;

#define GETN(j) g_pack[__builtin_amdgcn_readlane(((j) < 64 ? j_a : j_b), (j) & 63)]

    uint4 c0 = GETN(0), c1 = GETN(1), c2 = GETN(2), c3 = GETN(3);
#pragma unroll 1
    for (int g = 0; g < NNB / 4 - 1; ++g) {
        int j = 4 * g + 4;
        uint4 n0 = GETN(j), n1 = GETN(j + 1), n2 = GETN(j + 2), n3 = GETN(j + 3);
        accum_one(g_P2msg, c0, mw0, mb, mw0b, mbb, lane, acc0, acc1);
        accum_one(g_P2msg, c1, mw0, mb, mw0b, mbb, lane, acc0, acc1);
        accum_one(g_P2msg, c2, mw0, mb, mw0b, mbb, lane, acc0, acc1);
        accum_one(g_P2msg, c3, mw0, mb, mw0b, mbb, lane, acc0, acc1);
        c0 = n0; c1 = n1; c2 = n2; c3 = n3;
    }
    accum_one(g_P2msg, c0, mw0, mb, mw0b, mbb, lane, acc0, acc1);
    accum_one(g_P2msg, c1, mw0, mb, mw0b, mbb, lane, acc0, acc1);
    accum_one(g_P2msg, c2, mw0, mb, mw0b, mbb, lane, acc0, acc1);
    accum_one(g_P2msg, c3, mw0, mb, mw0b, mbb, lane, acc0, acc1);
#undef GETN

    float msg_a = acc0 * 0.01f;
    float msg_b = acc1 * 0.01f;   // lanes 0..2: dims 64..66

    // ---- Phase 2: per-edge MLP, all activations in registers ----
    int e0 = edges[2 * e], e1 = edges[2 * e + 1];

    const float* crow = combin_feats + (size_t)e0 * 31;
    int chid = (int)crow[30];
    float cx = 0.f;
    if (lane < 30)      cx = crow[lane];
    else if (lane < 46) cx = chemb[(size_t)chid * 16 + (lane - 30)];

    // d1 = relu(W_dev1 @ dev_x + b) via packed row + interleaved table
    float d1a = 0.f, d1b = 0.f;
    {
        uint4 r = g_pack[e1];
        accum_one(g_P2dev1, r, g_w0b_dev1[lane], g_w0b_dev1[67 + lane],
                  g_w0b_dev1[64 + lane], g_w0b_dev1[131 + lane], lane, d1a, d1b);
    }

    // ch = relu(W_ch1 @ combin_x + b)   I=46, O=27
    float s = g_bpad[lane];
    for (int k = 0; k < 46; k++) s += rl(cx, k) * g_Wt_ch1[k * 64 + lane];
    float ch = fmaxf(s, 0.f);

    // d2 = relu(W_dev2 @ d1 + b)        I=67, O=50
    s = g_bpad[64 + lane];
    for (int k = 0; k < 64; k++) s += rl(d1a, k) * g_Wt_dev2[k * 64 + lane];
    for (int k = 0; k < 3; k++)  s += rl(d1b, k) * g_Wt_dev2[(64 + k) * 64 + lane];
    float d2 = fmaxf(s, 0.f);

    // fus = relu(W_fus @ [ch|msg] + b)  I=94, O=56
    s = g_bpad[128 + lane];
    for (int k = 0; k < 27; k++) s += rl(ch, k) * g_Wt_fus[k * 64 + lane];
    for (int k = 0; k < 64; k++) s += rl(msg_a, k) * g_Wt_fus[(27 + k) * 64 + lane];
    for (int k = 0; k < 3; k++)  s += rl(msg_b, k) * g_Wt_fus[(91 + k) * 64 + lane];
    float fus = fmaxf(s, 0.f);

    // h1 = relu(W_c1 @ [fus|d2] + b)    I=106, O=63
    s = g_bpad[192 + lane];
    for (int k = 0; k < 56; k++) s += rl(fus, k) * g_Wt_c1[k * 64 + lane];
    for (int k = 0; k < 50; k++) s += rl(d2, k) * g_Wt_c1[(56 + k) * 64 + lane];
    float h1 = fmaxf(s, 0.f);

    // h2 = relu(W_c2 @ h1 + b)          I=63, O=31
    s = g_bpad[256 + lane];
    for (int k = 0; k < 63; k++) s += rl(h1, k) * g_Wt_c2[k * 64 + lane];
    float h2 = fmaxf(s, 0.f);

    // out = W_c3 @ h2 + b  (wave butterfly reduction)
    float t = (lane < 31) ? h2 * Wc3[lane] : 0.f;
    for (int off = 32; off; off >>= 1) t += __shfl_xor(t, off);
    if (lane == 0) out[e] = t + bc3[0];
}

extern "C" void kernel_launch(void* const* d_in, const int* in_sizes, int n_in,
                              void* d_out, int out_size, void* d_ws, size_t ws_size,
                              hipStream_t stream) {
    const float* combin   = (const float*)d_in[0];
    const float* devf     = (const float*)d_in[1];
    const float* chemb    = (const float*)d_in[2];
    const float* lang     = (const float*)d_in[3];
    const float* plat     = (const float*)d_in[4];
    const float* osb      = (const float*)d_in[5];
    const float* country  = (const float*)d_in[6];
    const float* carrier  = (const float*)d_in[7];
    const float* brand    = (const float*)d_in[8];
    const float* plat_os  = (const float*)d_in[9];
    const float* Wch1 = (const float*)d_in[10]; const float* bch1 = (const float*)d_in[11];
    const float* Wmsg = (const float*)d_in[12]; const float* bmsg = (const float*)d_in[13];
    const float* Wfus = (const float*)d_in[14]; const float* bfus = (const float*)d_in[15];
    const float* Wdev1 = (const float*)d_in[16]; const float* bdev1 = (const float*)d_in[17];
    const float* Wdev2 = (const float*)d_in[18]; const float* bdev2 = (const float*)d_in[19];
    const float* Wc1 = (const float*)d_in[20]; const float* bc1 = (const float*)d_in[21];
    const float* Wc2 = (const float*)d_in[22]; const float* bc2 = (const float*)d_in[23];
    const float* Wc3 = (const float*)d_in[24]; const float* bc3 = (const float*)d_in[25];
    const int* edges  = (const int*)d_in[26];
    const int* neibrs = (const int*)d_in[27];
    float* out = (float*)d_out;

    long long prep_threads = (long long)NDEV + 2LL * NP2HALF + 24064 + 320 + 268;
    int prep_blocks = (int)((prep_threads + 255) / 256);
    prep_kernel<<<prep_blocks, 256, 0, stream>>>(
        devf, lang, plat, osb, country, carrier, brand, plat_os,
        Wmsg, bmsg, Wdev1, bdev1, Wch1, bch1, Wdev2, bdev2,
        Wfus, bfus, Wc1, bc1, Wc2, bc2);

    fused_kernel<<<BATCH / 4, 256, 0, stream>>>(
        combin, chemb, edges, neibrs, Wc3, bc3, out);
}

// Round 4
// 106.846 us; speedup vs baseline: 1.7019x; 1.0392x over previous
//
#include <hip/hip_runtime.h>
#include <hip/hip_fp16.h>

#define BATCH 8192
#define NNB 100
#define NDEV 1000000

// Projected-table geometry: 2885 rows (lang 50, plat 5, os 30, country 200,
// carrier 500, brand 2000, plat_os 100), 67 output dims per row.
// Interleaved layout: g_P2*[row*64 + l] = {f16 P[row][l], f16 P[row][64+l]}
// (high half exact 0 for l>=3).
#define NROWS 2885
#define NP2HALF (NROWS * 64)   // 184640

// Static device storage (graph-capture safe).
__device__ __half2 g_P2msg[NP2HALF];
__device__ __half2 g_P2dev1[NP2HALF];
__device__ float g_w0b_msg[256];    // [0:67]=W[:,0], [67:134]=b, rest 0
__device__ float g_w0b_dev1[256];
__device__ uint4 g_pack[NDEV];      // {cont_f32, lo_idx, hi_idx, 0}
// Transposed weights, padded to output-stride 64 (zeros beyond O).
__device__ float g_Wt_ch1[46 * 64];
__device__ float g_Wt_dev2[67 * 64];
__device__ float g_Wt_fus[94 * 64];
__device__ float g_Wt_c1[106 * 64];
__device__ float g_Wt_c2[63 * 64];
__device__ float g_bpad[5 * 64];

__device__ __forceinline__ float rl(float v, int k) {
    return __uint_as_float(__builtin_amdgcn_readlane(__float_as_uint(v), (unsigned)k));
}

// One device's projected lookup. r is wave-uniform (SGPRs): table-base math
// runs on the SALU. Row sum accumulates in packed f16 (6 x v_pk_add_f16),
// converted to f32 once. acc1 is valid for lane<3 only (never read elsewhere).
__device__ __forceinline__ void accum_one(const __half2* __restrict__ P2, uint4 r,
    float mw0, float mb, float mw0b, float mbb, int lane, float& acc0, float& acc1)
{
    float cont = __uint_as_float(r.x);
    unsigned lo = r.y, hi = r.z;
    int b0 = ((int)(lo & 255u)) << 6;                  // lang
    int b1 = (50   + (int)((lo >> 8) & 255u)) << 6;    // plat
    int b2 = (55   + (int)((lo >> 16) & 255u)) << 6;   // os
    int b6 = (2785 + (int)(lo >> 24)) << 6;            // plat_os
    int b3 = (85   + (int)(hi & 511u)) << 6;           // country
    int b4 = (285  + (int)((hi >> 9) & 511u)) << 6;    // carrier
    int b5 = (785  + (int)(hi >> 20)) << 6;            // brand
    __half2 h0 = P2[b0 + lane], h1 = P2[b1 + lane], h2 = P2[b2 + lane];
    __half2 h3 = P2[b3 + lane], h4 = P2[b4 + lane], h5 = P2[b5 + lane];
    __half2 h6 = P2[b6 + lane];
    __half2 s01 = __hadd2(h0, h1), s23 = __hadd2(h2, h3), s45 = __hadd2(h4, h5);
    __half2 s = __hadd2(__hadd2(s01, s23), __hadd2(s45, h6));
    float2 f = __half22float2(s);
    float vm = fmaf(cont, mw0, mb) + f.x;
    float vt = fmaf(cont, mw0b, mbb) + f.y;
    acc0 += fmaxf(vm, 0.f);
    acc1 += fmaxf(vt, 0.f);
}

// ---------------------------------------------------------------------------
// Kernel A: pack device rows, build interleaved projected tables, transposed/
// padded weights, packed (W[:,0], b). One thread per output element.
// ---------------------------------------------------------------------------
__global__ __launch_bounds__(256) void prep_kernel(
    const float* __restrict__ devf,
    const float* __restrict__ lang, const float* __restrict__ plat,
    const float* __restrict__ osb, const float* __restrict__ country,
    const float* __restrict__ carrier, const float* __restrict__ brand,
    const float* __restrict__ plat_os,
    const float* __restrict__ Wmsg, const float* __restrict__ bmsg,
    const float* __restrict__ Wdev1, const float* __restrict__ bdev1,
    const float* __restrict__ Wch1, const float* __restrict__ bch1,
    const float* __restrict__ Wdev2, const float* __restrict__ bdev2,
    const float* __restrict__ Wfus, const float* __restrict__ bfus,
    const float* __restrict__ Wc1, const float* __restrict__ bc1,
    const float* __restrict__ Wc2, const float* __restrict__ bc2)
{
    int idx = blockIdx.x * 256 + threadIdx.x;
    if (idx < NDEV) {
        const float4* dr = (const float4*)(devf + (size_t)idx * 8);
        float4 a = dr[0], b4 = dr[1];
        unsigned lo = (unsigned)a.y | ((unsigned)a.z << 8)
                    | ((unsigned)a.w << 16) | ((unsigned)b4.w << 24);
        unsigned hi = (unsigned)b4.x | ((unsigned)b4.y << 9)
                    | ((unsigned)b4.z << 20);
        g_pack[idx] = make_uint4(__float_as_uint(a.x), lo, hi, 0u);
        return;
    }
    idx -= NDEV;
    if (idx < 2 * NP2HALF) {
        int which = idx / NP2HALF;        // 0 = msg, 1 = dev1
        int rem = idx - which * NP2HALF;
        int row = rem >> 6;
        int l = rem & 63;
        int t, r;
        if (row < 50)        { t = 0; r = row; }
        else if (row < 55)   { t = 1; r = row - 50; }
        else if (row < 85)   { t = 2; r = row - 55; }
        else if (row < 285)  { t = 3; r = row - 85; }
        else if (row < 785)  { t = 4; r = row - 285; }
        else if (row < 2785) { t = 5; r = row - 785; }
        else                 { t = 6; r = row - 2785; }
        const float* tab;
        switch (t) {
            case 0: tab = lang; break;    case 1: tab = plat; break;
            case 2: tab = osb; break;     case 3: tab = country; break;
            case 4: tab = carrier; break; case 5: tab = brand; break;
            default: tab = plat_os;
        }
        const float* e = tab + r * 16;
        const float* W = (which ? Wdev1 : Wmsg);
        const float* Wm = W + l * 113 + 1 + 16 * t;
        float m = 0.f;
#pragma unroll
        for (int j = 0; j < 16; j++) m += e[j] * Wm[j];
        float tl = 0.f;
        if (l < 3) {
            const float* Wt2 = W + (64 + l) * 113 + 1 + 16 * t;
#pragma unroll
            for (int j = 0; j < 16; j++) tl += e[j] * Wt2[j];
        }
        (which ? g_P2dev1 : g_P2msg)[rem] =
            __halves2half2(__float2half(m), __float2half(tl));
        return;
    }
    int l = idx - 2 * NP2HALF;
    if (l < 2944) { int k = l >> 6, o = l & 63; g_Wt_ch1[l]  = (o < 27) ? Wch1[o * 46 + k]  : 0.f; return; }
    l -= 2944;
    if (l < 4288) { int k = l >> 6, o = l & 63; g_Wt_dev2[l] = (o < 50) ? Wdev2[o * 67 + k] : 0.f; return; }
    l -= 4288;
    if (l < 6016) { int k = l >> 6, o = l & 63; g_Wt_fus[l]  = (o < 56) ? Wfus[o * 94 + k]  : 0.f; return; }
    l -= 6016;
    if (l < 6784) { int k = l >> 6, o = l & 63; g_Wt_c1[l]   = (o < 63) ? Wc1[o * 106 + k]  : 0.f; return; }
    l -= 6784;
    if (l < 4032) { int k = l >> 6, o = l & 63; g_Wt_c2[l]   = (o < 31) ? Wc2[o * 63 + k]   : 0.f; return; }
    l -= 4032;
    if (l < 320) {
        int which = l >> 6, o = l & 63;
        const float* b; int O;
        switch (which) {
            case 0: b = bch1; O = 27; break;  case 1: b = bdev2; O = 50; break;
            case 2: b = bfus; O = 56; break;  case 3: b = bc1; O = 63; break;
            default: b = bc2; O = 31;
        }
        g_bpad[l] = (o < O) ? b[o] : 0.f;
        return;
    }
    l -= 320;
    if (l < 268) {
        int which = l / 134, k = l - which * 134;
        float* dst = which ? g_w0b_dev1 : g_w0b_msg;
        const float* W = which ? Wdev1 : Wmsg;
        const float* b = which ? bdev1 : bmsg;
        dst[k] = (k < 67) ? W[k * 113] : b[k - 67];
    }
}

// ---------------------------------------------------------------------------
// Kernel B: one wave per edge. Phase 1: neighbor mean — scalar (s_load)
// neighbor indices + pack rows, software-pipelined one group of 4 ahead;
// per-table base math on SALU; packed-f16 row-sum on VALU. Phase 2: per-edge
// MLP fully in registers, lane = output neuron.
// ---------------------------------------------------------------------------
__global__ __launch_bounds__(256) void fused_kernel(
    const float* __restrict__ combin_feats, const float* __restrict__ chemb,
    const int* __restrict__ edges, const int* __restrict__ neibrs,
    const float* __restrict__ Wc3, const float* __restrict__ bc3,
    float* __restrict__ out)
{
    int gid = blockIdx.x * 256 + threadIdx.x;
    int e = gid >> 6;
    int lane = threadIdx.x & 63;
    int eu = __builtin_amdgcn_readfirstlane(e);   // wave-uniform edge id

    float mw0  = g_w0b_msg[lane];
    float mb   = g_w0b_msg[67 + lane];
    float mw0b = g_w0b_msg[64 + lane];    // valid lane<3; finite otherwise
    float mbb  = g_w0b_msg[131 + lane];

    const int4* nb4 = (const int4*)(neibrs + (size_t)eu * NNB);  // uniform ptr
    float acc0 = 0.f, acc1 = 0.f;

    int4 nn = nb4[0];
    uint4 c0 = g_pack[nn.x], c1 = g_pack[nn.y];
    uint4 c2 = g_pack[nn.z], c3 = g_pack[nn.w];
#pragma unroll 1
    for (int g = 0; g < NNB / 4 - 1; ++g) {
        int4 nx = nb4[g + 1];
        uint4 n0 = g_pack[nx.x], n1 = g_pack[nx.y];
        uint4 n2 = g_pack[nx.z], n3 = g_pack[nx.w];
        accum_one(g_P2msg, c0, mw0, mb, mw0b, mbb, lane, acc0, acc1);
        accum_one(g_P2msg, c1, mw0, mb, mw0b, mbb, lane, acc0, acc1);
        accum_one(g_P2msg, c2, mw0, mb, mw0b, mbb, lane, acc0, acc1);
        accum_one(g_P2msg, c3, mw0, mb, mw0b, mbb, lane, acc0, acc1);
        c0 = n0; c1 = n1; c2 = n2; c3 = n3;
    }
    accum_one(g_P2msg, c0, mw0, mb, mw0b, mbb, lane, acc0, acc1);
    accum_one(g_P2msg, c1, mw0, mb, mw0b, mbb, lane, acc0, acc1);
    accum_one(g_P2msg, c2, mw0, mb, mw0b, mbb, lane, acc0, acc1);
    accum_one(g_P2msg, c3, mw0, mb, mw0b, mbb, lane, acc0, acc1);

    float msg_a = acc0 * 0.01f;
    float msg_b = acc1 * 0.01f;   // lanes 0..2: dims 64..66

    // ---- Phase 2: per-edge MLP, all activations in registers ----
    int e0 = __builtin_amdgcn_readfirstlane(edges[2 * eu]);
    int e1 = __builtin_amdgcn_readfirstlane(edges[2 * eu + 1]);

    const float* crow = combin_feats + (size_t)e0 * 31;
    int chid = (int)crow[30];
    float cx = 0.f;
    if (lane < 30)      cx = crow[lane];
    else if (lane < 46) cx = chemb[(size_t)chid * 16 + (lane - 30)];

    // d1 = relu(W_dev1 @ dev_x + b) via packed row + interleaved table
    float d1a = 0.f, d1b = 0.f;
    {
        uint4 r = g_pack[e1];
        accum_one(g_P2dev1, r, g_w0b_dev1[lane], g_w0b_dev1[67 + lane],
                  g_w0b_dev1[64 + lane], g_w0b_dev1[131 + lane], lane, d1a, d1b);
    }

    // ch = relu(W_ch1 @ combin_x + b)   I=46, O=27
    float s = g_bpad[lane];
    for (int k = 0; k < 46; k++) s += rl(cx, k) * g_Wt_ch1[k * 64 + lane];
    float ch = fmaxf(s, 0.f);

    // d2 = relu(W_dev2 @ d1 + b)        I=67, O=50
    s = g_bpad[64 + lane];
    for (int k = 0; k < 64; k++) s += rl(d1a, k) * g_Wt_dev2[k * 64 + lane];
    for (int k = 0; k < 3; k++)  s += rl(d1b, k) * g_Wt_dev2[(64 + k) * 64 + lane];
    float d2 = fmaxf(s, 0.f);

    // fus = relu(W_fus @ [ch|msg] + b)  I=94, O=56
    s = g_bpad[128 + lane];
    for (int k = 0; k < 27; k++) s += rl(ch, k) * g_Wt_fus[k * 64 + lane];
    for (int k = 0; k < 64; k++) s += rl(msg_a, k) * g_Wt_fus[(27 + k) * 64 + lane];
    for (int k = 0; k < 3; k++)  s += rl(msg_b, k) * g_Wt_fus[(91 + k) * 64 + lane];
    float fus = fmaxf(s, 0.f);

    // h1 = relu(W_c1 @ [fus|d2] + b)    I=106, O=63
    s = g_bpad[192 + lane];
    for (int k = 0; k < 56; k++) s += rl(fus, k) * g_Wt_c1[k * 64 + lane];
    for (int k = 0; k < 50; k++) s += rl(d2, k) * g_Wt_c1[(56 + k) * 64 + lane];
    float h1 = fmaxf(s, 0.f);

    // h2 = relu(W_c2 @ h1 + b)          I=63, O=31
    s = g_bpad[256 + lane];
    for (int k = 0; k < 63; k++) s += rl(h1, k) * g_Wt_c2[k * 64 + lane];
    float h2 = fmaxf(s, 0.f);

    // out = W_c3 @ h2 + b  (wave butterfly reduction)
    float t = (lane < 31) ? h2 * Wc3[lane] : 0.f;
    for (int off = 32; off; off >>= 1) t += __shfl_xor(t, off);
    if (lane == 0) out[e] = t + bc3[0];
}

extern "C" void kernel_launch(void* const* d_in, const int* in_sizes, int n_in,
                              void* d_out, int out_size, void* d_ws, size_t ws_size,
                              hipStream_t stream) {
    const float* combin   = (const float*)d_in[0];
    const float* devf     = (const float*)d_in[1];
    const float* chemb    = (const float*)d_in[2];
    const float* lang     = (const float*)d_in[3];
    const float* plat     = (const float*)d_in[4];
    const float* osb      = (const float*)d_in[5];
    const float* country  = (const float*)d_in[6];
    const float* carrier  = (const float*)d_in[7];
    const float* brand    = (const float*)d_in[8];
    const float* plat_os  = (const float*)d_in[9];
    const float* Wch1 = (const float*)d_in[10]; const float* bch1 = (const float*)d_in[11];
    const float* Wmsg = (const float*)d_in[12]; const float* bmsg = (const float*)d_in[13];
    const float* Wfus = (const float*)d_in[14]; const float* bfus = (const float*)d_in[15];
    const float* Wdev1 = (const float*)d_in[16]; const float* bdev1 = (const float*)d_in[17];
    const float* Wdev2 = (const float*)d_in[18]; const float* bdev2 = (const float*)d_in[19];
    const float* Wc1 = (const float*)d_in[20]; const float* bc1 = (const float*)d_in[21];
    const float* Wc2 = (const float*)d_in[22]; const float* bc2 = (const float*)d_in[23];
    const float* Wc3 = (const float*)d_in[24]; const float* bc3 = (const float*)d_in[25];
    const int* edges  = (const int*)d_in[26];
    const int* neibrs = (const int*)d_in[27];
    float* out = (float*)d_out;

    long long prep_threads = (long long)NDEV + 2LL * NP2HALF + 24064 + 320 + 268;
    int prep_blocks = (int)((prep_threads + 255) / 256);
    prep_kernel<<<prep_blocks, 256, 0, stream>>>(
        devf, lang, plat, osb, country, carrier, brand, plat_os,
        Wmsg, bmsg, Wdev1, bdev1, Wch1, bch1, Wdev2, bdev2,
        Wfus, bfus, Wc1, bc1, Wc2, bc2);

    fused_kernel<<<BATCH / 4, 256, 0, stream>>>(
        combin, chemb, edges, neibrs, Wc3, bc3, out);
}